// Round 7
// baseline (246.133 us; speedup 1.0000x reference)
//
#include <hip/hip_runtime.h>
#include <hip/hip_bf16.h>
#include <math.h>

typedef unsigned short ushort_t;
typedef __bf16 bf16x8 __attribute__((ext_vector_type(8)));
typedef float f32x4 __attribute__((ext_vector_type(4)));

#define HIDDEN 896
#define NQH 14
#define NKVH 2
#define HD 64
#define SEQ 2048
#define NBATCH 4

__device__ inline ushort_t f2bf(float x) {
  union { float f; unsigned u; } c; c.f = x;
  unsigned r = c.u + 0x7FFFu + ((c.u >> 16) & 1u);
  return (ushort_t)(r >> 16);
}

__device__ inline unsigned pack2bf(float a, float b) {
  union { float f; unsigned u; } ca, cb; ca.f = a; cb.f = b;
  unsigned ua = ca.u + 0x8000u, ub = cb.u + 0x8000u;
  return __builtin_amdgcn_perm(ub, ua, 0x07060302);
}

// single-instruction pack: dst = {lo: bf16(a), hi: bf16(b)} (RNE)
__device__ inline unsigned cvtpk(float a, float b) {
  unsigned r;
  asm("v_cvt_pk_bf16_f32 %0, %1, %2" : "=v"(r) : "v"(a), "v"(b));
  return r;
}

__device__ inline bf16x8 ldfrag(const ushort_t* p) {
  return *reinterpret_cast<const bf16x8*>(p);
}

__device__ inline void async16(const ushort_t* g, ushort_t* l) {
  __builtin_amdgcn_global_load_lds(
      (const __attribute__((address_space(1))) void*)g,
      (__attribute__((address_space(3))) void*)l, 16, 0, 0);
}

// ---------------- prep ----------------

__device__ inline void transpose_sec(const float* __restrict__ in, ushort_t* __restrict__ out,
                                     int K, int N, int bx, int by) {
  __shared__ float tile[32][33];
  int k0 = by * 32, n0 = bx * 32;
  for (int r = threadIdx.y; r < 32; r += 8) {
    int k = k0 + r, n = n0 + threadIdx.x;
    tile[r][threadIdx.x] = (k < K && n < N) ? in[(size_t)k * N + n] : 0.f;
  }
  __syncthreads();
  for (int r = threadIdx.y; r < 32; r += 8) {
    int n = n0 + r, k = k0 + threadIdx.x;
    if (n < N && k < K) out[(size_t)n * K + k] = f2bf(tile[threadIdx.x][r]);
  }
}

__global__ void k_prep(const float* __restrict__ hidden, ushort_t* __restrict__ hb,
                       const float* __restrict__ Wq, const float* __restrict__ Wk,
                       const float* __restrict__ Wv, const float* __restrict__ Wo,
                       ushort_t* __restrict__ wT, ushort_t* __restrict__ woT,
                       float2* __restrict__ ctab) {
  const int blk = blockIdx.x;
  const int tid = threadIdx.y * 32 + threadIdx.x;
  if (blk < 7168) {
    int i = blk * 256 + tid;
    float4 v = reinterpret_cast<const float4*>(hidden)[i];
    ushort4 o;
    o.x = f2bf(v.x); o.y = f2bf(v.y); o.z = f2bf(v.z); o.w = f2bf(v.w);
    reinterpret_cast<ushort4*>(hb)[i] = o;
  } else if (blk < 7424) {
    int idx = (blk - 7168) * 256 + tid;
    int s = idx >> 5, dp = idx & 31;
    float inv = exp2f(-(float)dp * 0.41524101186092596f);
    float ang = (float)s * inv;
    float sn, cn;
    sincosf(ang, &sn, &cn);
    ctab[idx] = make_float2(cn, sn);
  } else if (blk < 8208) {
    int t = blk - 7424;
    transpose_sec(Wq, wT, 896, 896, t % 28, t / 28);
  } else if (blk < 8320) {
    int t = blk - 8208;
    transpose_sec(Wk, wT + (size_t)896 * 896, 896, 128, t % 4, t / 4);
  } else if (blk < 8432) {
    int t = blk - 8320;
    transpose_sec(Wv, wT + (size_t)1024 * 896, 896, 128, t % 4, t / 4);
  } else {
    int t = blk - 8432;
    transpose_sec(Wo, woT, 896, 896, t % 28, t / 28);
  }
}

// ---------------- QKV projection + RoPE (128x64 tiles, 32x64 wave-tile) ----------
// R1 verdict: 128x128 regressed from BLOCK-COUNT collapse. 128x64 keeps
// head-aligned N-sections, 1152 blocks (4.5/CU), LDS 24KB, bytes/FLOP x0.75.
// grid: 1152 blocks 1D (64 m-tiles x 18 n-sections), XCD-swizzled.
// sect 0..13 = Q head; 14..15 = K kvh; 16..17 = V kvh.
__global__ __launch_bounds__(256) void k_qkv(
    const ushort_t* __restrict__ hb,
    const ushort_t* __restrict__ wT,
    const int* __restrict__ pos_ids,
    const float2* __restrict__ ctab,
    ushort_t* __restrict__ Qg,
    ushort_t* __restrict__ Kg,
    ushort_t* __restrict__ Vtg) {
  __shared__ ushort_t smem[12288];   // sa [0,8192) 128x64, sbb [8192,12288) 64x64
  ushort_t* sa = smem;
  ushort_t* sbb = smem + 8192;

  const int f = blockIdx.x;
  const int x = f & 7, s8 = f >> 3;       // s8: 0..143
  const int sect = s8 % 18;
  const int mt = (s8 / 18) * 8 + x;       // 0..63
  const int nt0 = sect * 64;
  const int m0 = mt * 128;
  const int tid = threadIdx.x;
  const int wave = tid >> 6, lane = tid & 63;
  const int l15 = lane & 15, quad = lane >> 4;
  const int sw = l15 & 7;

  f32x4 acc[2][4];
  const f32x4 z4 = {0.f, 0.f, 0.f, 0.f};
#pragma unroll
  for (int mm = 0; mm < 2; ++mm)
#pragma unroll
    for (int nb = 0; nb < 4; ++nb) acc[mm][nb] = z4;

  for (int kt = 0; kt < 14; ++kt) {
    const int k0 = kt * 64;
    __syncthreads();
#pragma unroll
    for (int i = 0; i < 4; ++i) {
      int id = i * 256 + tid;
      int row = id >> 3;                  // 0..127
      int cs = (id & 7) ^ (row & 7);
      async16(hb + (size_t)(m0 + row) * HIDDEN + k0 + cs * 8, sa + (i * 256 + wave * 64) * 8);
    }
#pragma unroll
    for (int i = 0; i < 2; ++i) {
      int id = i * 256 + tid;
      int row = id >> 3;                  // 0..63
      int cs = (id & 7) ^ (row & 7);
      async16(wT + (size_t)(nt0 + row) * HIDDEN + k0 + cs * 8, sbb + (i * 256 + wave * 64) * 8);
    }
    __syncthreads();
#pragma unroll
    for (int kc = 0; kc < 2; ++kc) {
      int c = kc * 4 + quad;
      bf16x8 af[2], bf[4];
#pragma unroll
      for (int mm = 0; mm < 2; ++mm)
        af[mm] = ldfrag(sa + ((wave * 32 + mm * 16 + l15) * 8 + (c ^ sw)) * 8);
#pragma unroll
      for (int nb = 0; nb < 4; ++nb)
        bf[nb] = ldfrag(sbb + ((nb * 16 + l15) * 8 + (c ^ sw)) * 8);
#pragma unroll
      for (int mm = 0; mm < 2; ++mm)
#pragma unroll
        for (int nb = 0; nb < 4; ++nb)
          acc[mm][nb] = __builtin_amdgcn_mfma_f32_16x16x32_bf16(af[mm], bf[nb], acc[mm][nb], 0, 0, 0);
    }
  }

  if (sect < 16) {
    const bool isQ = sect < 14;
    const float csc = isQ ? 0.125f * 1.4426950408889634f : 1.0f;
    ushort_t* dst = isQ ? Qg : Kg;
    const int nheads = isQ ? NQH : NKVH;
    const int hh = isQ ? sect : sect - 14;
#pragma unroll
    for (int mm = 0; mm < 2; ++mm) {
#pragma unroll
      for (int r = 0; r < 4; ++r) {
        int token = m0 + wave * 32 + mm * 16 + quad * 4 + r;
        int b = token >> 11, s = token & 2047;
        int pos = pos_ids[token];
        size_t base = ((size_t)(b * nheads + hh) * SEQ + s) * HD;
#pragma unroll
        for (int nb = 0; nb < 2; ++nb) {
          float2 cs = ctab[pos * 32 + nb * 16 + l15];
          float x0 = acc[mm][nb][r];
          float x1 = acc[mm][nb + 2][r];
          float y0 = (x0 * cs.x - x1 * cs.y) * csc;
          float y1 = (x1 * cs.x + x0 * cs.y) * csc;
          dst[base + nb * 16 + l15]      = f2bf(y0);
          dst[base + nb * 16 + l15 + 32] = f2bf(y1);
        }
      }
    }
  } else {
    const int kvh = sect - 16;
    __syncthreads();
    ushort_t* vt = smem;  // 64 d-rows x 128 tokens = 8192 ushorts (16KB of 24KB)
#pragma unroll
    for (int mm = 0; mm < 2; ++mm) {
      int tl = wave * 32 + mm * 16 + quad * 4;   // token base (r=0..3), 0..124
      int chunk = tl >> 3, ofs = tl & 7;         // chunk 0..15, ofs = 0 or 4
#pragma unroll
      for (int nb = 0; nb < 4; ++nb) {
        int row = nb * 16 + l15;                 // d
        int slot = chunk ^ (row & 7);            // XOR low 3 bits of 4-bit chunk
        ushort_t* p = vt + row * 128 + slot * 8 + ofs;
        *reinterpret_cast<unsigned*>(p)     = pack2bf(acc[mm][nb][0], acc[mm][nb][1]);
        *reinterpret_cast<unsigned*>(p + 2) = pack2bf(acc[mm][nb][2], acc[mm][nb][3]);
      }
    }
    __syncthreads();
    const int bb = m0 >> 11, s0 = m0 & 2047;
#pragma unroll
    for (int i = 0; i < 4; ++i) {
      int id = i * 256 + tid;          // 1024 chunks: 64 rows x 16 chunks
      int row = id >> 4, ch = id & 15;
      int slot = ch ^ (row & 7);
      uint4 v = *reinterpret_cast<const uint4*>(vt + row * 128 + slot * 8);
      *reinterpret_cast<uint4*>(Vtg + ((size_t)(bb * NKVH + kvh) * HD + row) * SEQ + s0 + ch * 8) = v;
    }
  }
}

// ---------------- flash attention (R7: 2-wave blocks, QBLK=64, 7 blocks/CU) -------
// grid: 1792 blocks x 128 threads. XCD x owns (b,kvh): b=x>>1, kvh=x&1.
// R6 post-mortem: VALU floor reached for this structure (45% busy = intrinsic
// exp2/sum/pack work); 29% of cycles idle on BOTH pipes with occupancy stuck at
// 29% -- the 896-block grid gives only 3.5 blocks/CU (uneven 3/4 split + tail).
// This round: halve block to 2 waves (QBLK=64), double grid to 1792 = exactly
// 7.0 blocks/CU; LDS 21.5KB -> LDS cap 7 -> all blocks resident, zero tail.
// Per-wave code identical; only staging index map (2 chunks/thread) + qt change.
__global__ __launch_bounds__(128) void k_attn(
    const ushort_t* __restrict__ Qg,
    const ushort_t* __restrict__ Kg,
    const ushort_t* __restrict__ Vtg,
    ushort_t* __restrict__ attn) {
  __shared__ ushort_t kbuf[2][32 * 64];   // 32 keys x 64 d, 8-chunk XOR swizzle
  __shared__ ushort_t vbuf[2][64 * 32];   // 64 d x 32 tokens, 4-chunk swizzle (row>>1)
  __shared__ ushort_t pbuf[2][32 * 40];   // per-wave P: 32 q-rows x (32 keys + 8 pad)

  const int f = blockIdx.x;
  const int x = f & 7, s8 = f >> 3;     // s8: 0..223
  const int lh = s8 % 7;
  const int qt = s8 / 7;                // 0..31
  const int b = x >> 1, kvh = x & 1;
  const int h = kvh * 7 + lh;
  const int bh = b * NQH + h;
  const int tid = threadIdx.x;          // 0..127
  const int wave = tid >> 6, lane = tid & 63;
  const int l15 = lane & 15, quad = lane >> 4;
  const int q0 = qt * 64;

  bf16x8 qf[2][2];
#pragma unroll
  for (int qs = 0; qs < 2; ++qs) {
    const size_t qb = ((size_t)bh * SEQ + q0 + wave * 32 + qs * 16 + l15) * HD + quad * 8;
    qf[qs][0] = ldfrag(Qg + qb);
    qf[qs][1] = ldfrag(Qg + qb + 32);
  }

  const size_t kbase = (size_t)(b * NKVH + kvh) * SEQ * HD;
  const size_t vbase = (size_t)(b * NKVH + kvh) * HD * SEQ;

  // staging: 256 K-chunks + 256 V-chunks over 128 threads = 2+2 per thread.
  // chunk c (lane-varying): iter i covers c = i*128+tid. dest linear at chunk id;
  // source row/col inverse-swizzled (K: 8-slot by row&7; V: 4-slot by (row>>1)&3).
  const int cA = tid, cB = 128 + tid;
  const int krA = cA >> 3, kcA = (cA & 7) ^ (krA & 7);
  const int krB = cB >> 3, kcB = (cB & 7) ^ (krB & 7);
  const int vrA = cA >> 2, vcA = (cA & 3) ^ ((vrA >> 1) & 3);
  const int vrB = cB >> 2, vcB = (cB & 3) ^ ((vrB >> 1) & 3);

  // running global source pointers (bumped one 32-token tile per stage)
  const ushort_t* kgA = Kg + kbase + (size_t)krA * HD + kcA * 8;
  const ushort_t* kgB = Kg + kbase + (size_t)krB * HD + kcB * 8;
  const ushort_t* vgA = Vtg + vbase + (size_t)vrA * SEQ + vcA * 8;
  const ushort_t* vgB = Vtg + vbase + (size_t)vrB * SEQ + vcB * 8;

  // wave-uniform LDS dest bases (ushorts): iter A -> chunks wave*64.., iter B -> 128+wave*64..
  const int dstA = wave * 64 * 8;
  const int dstB = (128 + wave * 64) * 8;

  float l_part[2] = {0.f, 0.f};
  f32x4 o[2][4];
  const f32x4 z4 = {0.f, 0.f, 0.f, 0.f};
#pragma unroll
  for (int qs = 0; qs < 2; ++qs)
#pragma unroll
    for (int nb = 0; nb < 4; ++nb) o[qs][nb] = z4;

  ushort_t* pw = pbuf[wave];

  auto stage = [&](ushort_t* kb, ushort_t* vb) {
    async16(kgA, kb + dstA);
    async16(kgB, kb + dstB);
    async16(vgA, vb + dstA);
    async16(vgB, vb + dstB);
    kgA += 32 * HD; kgB += 32 * HD;
    vgA += 32; vgB += 32;
  };

  auto compute = [&](const ushort_t* kb, const ushort_t* vb) {
#pragma unroll
    for (int nb = 0; nb < 2; ++nb) {
      int row = nb * 16 + l15;
      int swz = row & 7;
      bf16x8 kf0 = ldfrag(kb + (row * 8 + (quad ^ swz)) * 8);
      bf16x8 kf1 = ldfrag(kb + (row * 8 + ((4 + quad) ^ swz)) * 8);
#pragma unroll
      for (int qs = 0; qs < 2; ++qs) {
        f32x4 t = z4;
        t = __builtin_amdgcn_mfma_f32_16x16x32_bf16(kf0, qf[qs][0], t, 0, 0, 0);
        t = __builtin_amdgcn_mfma_f32_16x16x32_bf16(kf1, qf[qs][1], t, 0, 0, 0);
        float p0 = __builtin_amdgcn_exp2f(t[0]);
        float p1 = __builtin_amdgcn_exp2f(t[1]);
        float p2 = __builtin_amdgcn_exp2f(t[2]);
        float p3 = __builtin_amdgcn_exp2f(t[3]);
        l_part[qs] += (p0 + p1) + (p2 + p3);
        uint2 d;
        d.x = cvtpk(p0, p1);
        d.y = cvtpk(p2, p3);
        *reinterpret_cast<uint2*>(pw + (qs * 16 + l15) * 40 + nb * 16 + quad * 4) = d;
      }
    }

    bf16x8 pf[2];
#pragma unroll
    for (int qs = 0; qs < 2; ++qs)
      pf[qs] = ldfrag(pw + (qs * 16 + l15) * 40 + quad * 8);
#pragma unroll
    for (int nb = 0; nb < 4; ++nb) {
      int row = nb * 16 + l15;
      bf16x8 vf = ldfrag(vb + row * 32 + ((quad ^ ((row >> 1) & 3)) * 8));
#pragma unroll
      for (int qs = 0; qs < 2; ++qs)
        o[qs][nb] = __builtin_amdgcn_mfma_f32_16x16x32_bf16(pf[qs], vf, o[qs][nb], 0, 0, 0);
    }
  };

  // prologue: stage tile 0, drain (also covers qf loads), barrier
  stage(kbuf[0], vbuf[0]);
  asm volatile("s_waitcnt vmcnt(0)" ::: "memory");
  __builtin_amdgcn_s_barrier();
  __builtin_amdgcn_sched_barrier(0);

  for (int jt = 0; jt < 62; jt += 2) {
    stage(kbuf[1], vbuf[1]);            // tile jt+1
    compute(kbuf[0], vbuf[0]);          // tile jt
    __builtin_amdgcn_sched_barrier(0);
    asm volatile("s_waitcnt vmcnt(0)" ::: "memory");
    __builtin_amdgcn_s_barrier();
    __builtin_amdgcn_sched_barrier(0);

    stage(kbuf[0], vbuf[0]);            // tile jt+2
    compute(kbuf[1], vbuf[1]);          // tile jt+1
    __builtin_amdgcn_sched_barrier(0);
    asm volatile("s_waitcnt vmcnt(0)" ::: "memory");
    __builtin_amdgcn_s_barrier();
    __builtin_amdgcn_sched_barrier(0);
  }
  // tiles 62 (in buf0) and 63
  stage(kbuf[1], vbuf[1]);              // tile 63
  compute(kbuf[0], vbuf[0]);            // tile 62
  __builtin_amdgcn_sched_barrier(0);
  asm volatile("s_waitcnt vmcnt(0)" ::: "memory");
  __builtin_amdgcn_s_barrier();
  __builtin_amdgcn_sched_barrier(0);
  compute(kbuf[1], vbuf[1]);            // tile 63

#pragma unroll
  for (int qs = 0; qs < 2; ++qs) {
    float s = l_part[qs];
    s += __shfl_xor(s, 16);
    s += __shfl_xor(s, 32);
    l_part[qs] = s;
  }

#pragma unroll
  for (int qs = 0; qs < 2; ++qs) {
    float il = 1.0f / l_part[qs];
#pragma unroll
    for (int r = 0; r < 4; ++r) {
      float inv = __shfl(il, quad * 4 + r);
      int qg = q0 + wave * 32 + qs * 16 + quad * 4 + r;
#pragma unroll
      for (int nb = 0; nb < 4; ++nb) {
        float val = o[qs][nb][r] * inv;
        attn[(size_t)(b * SEQ + qg) * (NQH * HD) + h * HD + nb * 16 + l15] = f2bf(val);
      }
    }
  }
}

// ---------------- output projection (128x64 tiles, 32x64 wave-tile) ----------------
// grid: 896 blocks 1D (64 m-tiles x 14 n-sections), XCD-swizzled; 3.5 blocks/CU.
__global__ __launch_bounds__(256) void k_oproj(
    const ushort_t* __restrict__ attn,
    const ushort_t* __restrict__ woT,
    float* __restrict__ out) {
  __shared__ ushort_t smem[12288];
  ushort_t* sa = smem;
  ushort_t* sbb = smem + 8192;

  const int f = blockIdx.x;
  const int x = f & 7, s8 = f >> 3;   // s8: 0..111
  const int n_sect = s8 % 14;
  const int mt = (s8 / 14) * 8 + x;   // 0..63
  const int n0 = n_sect * 64;
  const int m0 = mt * 128;
  const int tid = threadIdx.x;
  const int wave = tid >> 6, lane = tid & 63;
  const int l15 = lane & 15, quad = lane >> 4;
  const int sw = l15 & 7;

  f32x4 acc[2][4];
  const f32x4 z4 = {0.f, 0.f, 0.f, 0.f};
#pragma unroll
  for (int mm = 0; mm < 2; ++mm)
#pragma unroll
    for (int nb = 0; nb < 4; ++nb) acc[mm][nb] = z4;

  for (int kt = 0; kt < 14; ++kt) {
    const int k0 = kt * 64;
    __syncthreads();
#pragma unroll
    for (int i = 0; i < 4; ++i) {
      int id = i * 256 + tid;
      int row = id >> 3;                // 0..127
      int cs = (id & 7) ^ (row & 7);
      async16(attn + (size_t)(m0 + row) * HIDDEN + k0 + cs * 8, sa + (i * 256 + wave * 64) * 8);
    }
#pragma unroll
    for (int i = 0; i < 2; ++i) {
      int id = i * 256 + tid;
      int row = id >> 3;                // 0..63
      int cs = (id & 7) ^ (row & 7);
      async16(woT + (size_t)(n0 + row) * HIDDEN + k0 + cs * 8, sbb + (i * 256 + wave * 64) * 8);
    }
    __syncthreads();
#pragma unroll
    for (int kc = 0; kc < 2; ++kc) {
      int c = kc * 4 + quad;
      bf16x8 af[2], bf[4];
#pragma unroll
      for (int mm = 0; mm < 2; ++mm)
        af[mm] = ldfrag(sa + ((wave * 32 + mm * 16 + l15) * 8 + (c ^ sw)) * 8);
#pragma unroll
      for (int nb = 0; nb < 4; ++nb)
        bf[nb] = ldfrag(sbb + ((nb * 16 + l15) * 8 + (c ^ sw)) * 8);
#pragma unroll
      for (int mm = 0; mm < 2; ++mm)
#pragma unroll
        for (int nb = 0; nb < 4; ++nb)
          acc[mm][nb] = __builtin_amdgcn_mfma_f32_16x16x32_bf16(af[mm], bf[nb], acc[mm][nb], 0, 0, 0);
    }
  }

#pragma unroll
  for (int mm = 0; mm < 2; ++mm)
#pragma unroll
    for (int nb = 0; nb < 4; ++nb)
#pragma unroll
      for (int r = 0; r < 4; ++r)
        out[(size_t)(m0 + wave * 32 + mm * 16 + quad * 4 + r) * HIDDEN +
            n0 + nb * 16 + l15] = acc[mm][nb][r];
}

// ---------------- launch ----------------

extern "C" void kernel_launch(void* const* d_in, const int* in_sizes, int n_in,
                              void* d_out, int out_size, void* d_ws, size_t ws_size,
                              hipStream_t stream) {
  (void)in_sizes; (void)n_in; (void)out_size; (void)ws_size;
  const float* hidden = (const float*)d_in[0];
  const int* pos      = (const int*)d_in[1];
  const float* Wq     = (const float*)d_in[2];
  const float* Wk     = (const float*)d_in[3];
  const float* Wv     = (const float*)d_in[4];
  const float* Wo     = (const float*)d_in[5];
  float* out = (float*)d_out;

  char* ws = (char*)d_ws;
  ushort_t* hb   = (ushort_t*)(ws);               // [8192][896] bf16   14,680,064
  ushort_t* wT   = (ushort_t*)(ws + 14680064);    // [1152][896] bf16    2,064,384
  float2*   ctab = (float2*)  (ws + 16744448);    // [2048][32]            524,288
  ushort_t* Qg   = (ushort_t*)(ws + 17268736);    // [4][14][2048][64]  14,680,064
  ushort_t* Kg   = (ushort_t*)(ws + 31948800);    // [4][2][2048][64]    2,097,152
  ushort_t* Vtg  = (ushort_t*)(ws + 34045952);    // [4][2][64][2048]    2,097,152
  ushort_t* attn = (ushort_t*)(ws + 36143104);    // [8192][896] bf16   14,680,064
  ushort_t* woT  = (ushort_t*)(ws + 50823168);    // [896][896] bf16     1,605,632

  k_prep<<<9216, dim3(32, 8), 0, stream>>>(hidden, hb, Wq, Wk, Wv, Wo, wT, woT, ctab);
  k_qkv<<<1152, 256, 0, stream>>>(hb, wT, pos, ctab, Qg, Kg, Vtg);
  k_attn<<<1792, 128, 0, stream>>>(Qg, Kg, Vtg, attn);
  k_oproj<<<896, 256, 0, stream>>>(attn, woT, out);
}

// Round 8
// 229.672 us; speedup vs baseline: 1.0717x; 1.0717x over previous
//
#include <hip/hip_runtime.h>
#include <hip/hip_bf16.h>
#include <math.h>

typedef unsigned short ushort_t;
typedef __bf16 bf16x8 __attribute__((ext_vector_type(8)));
typedef float f32x4 __attribute__((ext_vector_type(4)));

#define HIDDEN 896
#define NQH 14
#define NKVH 2
#define HD 64
#define SEQ 2048
#define NBATCH 4

__device__ inline ushort_t f2bf(float x) {
  union { float f; unsigned u; } c; c.f = x;
  unsigned r = c.u + 0x7FFFu + ((c.u >> 16) & 1u);
  return (ushort_t)(r >> 16);
}

__device__ inline unsigned pack2bf(float a, float b) {
  union { float f; unsigned u; } ca, cb; ca.f = a; cb.f = b;
  unsigned ua = ca.u + 0x8000u, ub = cb.u + 0x8000u;
  return __builtin_amdgcn_perm(ub, ua, 0x07060302);
}

// single-instruction pack: dst = {lo: bf16(a), hi: bf16(b)} (RNE)
__device__ inline unsigned cvtpk(float a, float b) {
  unsigned r;
  asm("v_cvt_pk_bf16_f32 %0, %1, %2" : "=v"(r) : "v"(a), "v"(b));
  return r;
}

__device__ inline bf16x8 ldfrag(const ushort_t* p) {
  return *reinterpret_cast<const bf16x8*>(p);
}

__device__ inline void async16(const ushort_t* g, ushort_t* l) {
  __builtin_amdgcn_global_load_lds(
      (const __attribute__((address_space(1))) void*)g,
      (__attribute__((address_space(3))) void*)l, 16, 0, 0);
}

// ---------------- prep ----------------

__device__ inline void transpose_sec(const float* __restrict__ in, ushort_t* __restrict__ out,
                                     int K, int N, int bx, int by) {
  __shared__ float tile[32][33];
  int k0 = by * 32, n0 = bx * 32;
  for (int r = threadIdx.y; r < 32; r += 8) {
    int k = k0 + r, n = n0 + threadIdx.x;
    tile[r][threadIdx.x] = (k < K && n < N) ? in[(size_t)k * N + n] : 0.f;
  }
  __syncthreads();
  for (int r = threadIdx.y; r < 32; r += 8) {
    int n = n0 + r, k = k0 + threadIdx.x;
    if (n < N && k < K) out[(size_t)n * K + k] = f2bf(tile[threadIdx.x][r]);
  }
}

__global__ void k_prep(const float* __restrict__ hidden, ushort_t* __restrict__ hb,
                       const float* __restrict__ Wq, const float* __restrict__ Wk,
                       const float* __restrict__ Wv, const float* __restrict__ Wo,
                       ushort_t* __restrict__ wT, ushort_t* __restrict__ woT,
                       float2* __restrict__ ctab) {
  const int blk = blockIdx.x;
  const int tid = threadIdx.y * 32 + threadIdx.x;
  if (blk < 7168) {
    int i = blk * 256 + tid;
    float4 v = reinterpret_cast<const float4*>(hidden)[i];
    ushort4 o;
    o.x = f2bf(v.x); o.y = f2bf(v.y); o.z = f2bf(v.z); o.w = f2bf(v.w);
    reinterpret_cast<ushort4*>(hb)[i] = o;
  } else if (blk < 7424) {
    int idx = (blk - 7168) * 256 + tid;
    int s = idx >> 5, dp = idx & 31;
    float inv = exp2f(-(float)dp * 0.41524101186092596f);
    float ang = (float)s * inv;
    float sn, cn;
    sincosf(ang, &sn, &cn);
    ctab[idx] = make_float2(cn, sn);
  } else if (blk < 8208) {
    int t = blk - 7424;
    transpose_sec(Wq, wT, 896, 896, t % 28, t / 28);
  } else if (blk < 8320) {
    int t = blk - 8208;
    transpose_sec(Wk, wT + (size_t)896 * 896, 896, 128, t % 4, t / 4);
  } else if (blk < 8432) {
    int t = blk - 8320;
    transpose_sec(Wv, wT + (size_t)1024 * 896, 896, 128, t % 4, t / 4);
  } else {
    int t = blk - 8432;
    transpose_sec(Wo, woT, 896, 896, t % 28, t / 28);
  }
}

// ---------------- QKV projection + RoPE (R8: BK=32, 3-buffer counted-vmcnt pipeline) ----
// R6 residue analysis: GEMM time flat across tile shapes -> the 2x full vmcnt(0)
// drains per K-step are the cost (T4 lever unapplied). This round: BK=32 tiles,
// THREE 12KB LDS buffers (36KB); per step stage tile t+2, compute tile t, then
// s_waitcnt vmcnt(3) (never 0) + raw s_barrier -> each tile's loads get a full
// step of slack; no drain in the main loop. Period-3 unroll keeps buffer bases
// literal; last iter peeled (dead prefetch re-stages tile 27; addresses in-bounds).
// grid: 1152 blocks (64 m-tiles x 18 n-sections), XCD-swizzled.
// sect 0..13 = Q head; 14..15 = K kvh; 16..17 = V kvh.
__global__ __launch_bounds__(256) void k_qkv(
    const ushort_t* __restrict__ hb,
    const ushort_t* __restrict__ wT,
    const int* __restrict__ pos_ids,
    const float2* __restrict__ ctab,
    ushort_t* __restrict__ Qg,
    ushort_t* __restrict__ Kg,
    ushort_t* __restrict__ Vtg) {
  __shared__ ushort_t smem[18432];  // 3 bufs x 6144 (A 128x32 @0, B 64x32 @4096); V epi reuses [0,8192)

  const int f = blockIdx.x;
  const int x = f & 7, s8 = f >> 3;       // s8: 0..143
  const int sect = s8 % 18;
  const int mt = (s8 / 18) * 8 + x;       // 0..63
  const int nt0 = sect * 64;
  const int m0 = mt * 128;
  const int tid = threadIdx.x;
  const int wave = tid >> 6, lane = tid & 63;
  const int l15 = lane & 15, quad = lane >> 4;
  const int c4 = quad ^ ((l15 >> 1) & 3);   // 4-slot read swizzle (64B rows)

  f32x4 acc[2][4];
  const f32x4 z4 = {0.f, 0.f, 0.f, 0.f};
#pragma unroll
  for (int mm = 0; mm < 2; ++mm)
#pragma unroll
    for (int nb = 0; nb < 4; ++nb) acc[mm][nb] = z4;

  // staging maps: A 512 chunks (2/thread), B 256 chunks (1/thread); dest linear,
  // source col inverse-swizzled with the same 4-slot involution.
  const int cA1 = 256 + tid;
  const int rA0 = tid >> 2,  sA0 = (tid & 3) ^ ((rA0 >> 1) & 3);
  const int rA1 = cA1 >> 2,  sA1 = (cA1 & 3) ^ ((rA1 >> 1) & 3);
  const int rB  = tid >> 2,  sB  = (tid & 3) ^ ((rB >> 1) & 3);
  const ushort_t* pA0 = hb + (size_t)(m0 + rA0) * HIDDEN + sA0 * 8;
  const ushort_t* pA1 = hb + (size_t)(m0 + rA1) * HIDDEN + sA1 * 8;
  const ushort_t* pB  = wT + (size_t)(nt0 + rB) * HIDDEN + sB * 8;
  const int dA0 = (wave * 64) * 8;          // wave-uniform LDS dest bases
  const int dA1 = 2048 + (wave * 64) * 8;
  const int dB  = 4096 + (wave * 64) * 8;

  ushort_t* const b0 = smem;
  ushort_t* const b1 = smem + 6144;
  ushort_t* const b2 = smem + 12288;

  auto stage = [&](int off, ushort_t* buf) {   // off in elements (tile col delta)
    async16(pA0 + off, buf + dA0);
    async16(pA1 + off, buf + dA1);
    async16(pB + off, buf + dB);
  };

  auto compute = [&](const ushort_t* buf) {
    bf16x8 af[2], bf[4];
#pragma unroll
    for (int mm = 0; mm < 2; ++mm)
      af[mm] = ldfrag(buf + (wave * 32 + mm * 16 + l15) * 32 + c4 * 8);
#pragma unroll
    for (int nb = 0; nb < 4; ++nb)
      bf[nb] = ldfrag(buf + 4096 + (nb * 16 + l15) * 32 + c4 * 8);
#pragma unroll
    for (int mm = 0; mm < 2; ++mm)
#pragma unroll
      for (int nb = 0; nb < 4; ++nb)
        acc[mm][nb] = __builtin_amdgcn_mfma_f32_16x16x32_bf16(af[mm], bf[nb], acc[mm][nb], 0, 0, 0);
  };

#define QKV_SYNC() \
  __builtin_amdgcn_sched_barrier(0); \
  asm volatile("s_waitcnt vmcnt(3)" ::: "memory"); \
  __builtin_amdgcn_s_barrier(); \
  __builtin_amdgcn_sched_barrier(0);

  // prologue: stage tiles 0,1; wait tile 0 (leave tile 1 in flight)
  stage(0, b0);
  stage(32, b1);
  QKV_SYNC();
  pA0 += 64; pA1 += 64; pB += 64;   // point at tile-2 col base

  for (int i = 0; i < 8; ++i) {     // tiles 3i..3i+2; stage 3i+2..3i+4
    stage(0, b2);  compute(b0);  QKV_SYNC();
    stage(32, b0); compute(b1);  QKV_SYNC();
    stage(64, b1); compute(b2);  QKV_SYNC();
    pA0 += 96; pA1 += 96; pB += 96;
  }
  // peeled final group: tiles 24,25,26; stage 26,27,27(dead, in-bounds)
  stage(0, b2);  compute(b0);  QKV_SYNC();
  stage(32, b0); compute(b1);  QKV_SYNC();
  stage(32, b1); compute(b2);  QKV_SYNC();
  compute(b0);                      // tile 27 (ready: its loads waited at prev sync)
#undef QKV_SYNC

  if (sect < 16) {
    const bool isQ = sect < 14;
    const float csc = isQ ? 0.125f * 1.4426950408889634f : 1.0f;
    ushort_t* dst = isQ ? Qg : Kg;
    const int nheads = isQ ? NQH : NKVH;
    const int hh = isQ ? sect : sect - 14;
#pragma unroll
    for (int mm = 0; mm < 2; ++mm) {
#pragma unroll
      for (int r = 0; r < 4; ++r) {
        int token = m0 + wave * 32 + mm * 16 + quad * 4 + r;
        int b = token >> 11, s = token & 2047;
        int pos = pos_ids[token];
        size_t base = ((size_t)(b * nheads + hh) * SEQ + s) * HD;
#pragma unroll
        for (int nb = 0; nb < 2; ++nb) {
          float2 cs = ctab[pos * 32 + nb * 16 + l15];
          float x0 = acc[mm][nb][r];
          float x1 = acc[mm][nb + 2][r];
          float y0 = (x0 * cs.x - x1 * cs.y) * csc;
          float y1 = (x1 * cs.x + x0 * cs.y) * csc;
          dst[base + nb * 16 + l15]      = f2bf(y0);
          dst[base + nb * 16 + l15 + 32] = f2bf(y1);
        }
      }
    }
  } else {
    const int kvh = sect - 16;
    // dead prefetch DMAs may still target b1 (overlaps vt): drain ALL waves first.
    asm volatile("s_waitcnt vmcnt(0)" ::: "memory");
    __syncthreads();
    ushort_t* vt = smem;  // 64 d-rows x 128 tokens = 8192 ushorts
#pragma unroll
    for (int mm = 0; mm < 2; ++mm) {
      int tl = wave * 32 + mm * 16 + quad * 4;   // token base (r=0..3)
      int chunk = tl >> 3, ofs = tl & 7;         // chunk 0..15, ofs = 0 or 4
#pragma unroll
      for (int nb = 0; nb < 4; ++nb) {
        int row = nb * 16 + l15;                 // d
        int slot = chunk ^ (row & 7);
        ushort_t* p = vt + row * 128 + slot * 8 + ofs;
        *reinterpret_cast<unsigned*>(p)     = pack2bf(acc[mm][nb][0], acc[mm][nb][1]);
        *reinterpret_cast<unsigned*>(p + 2) = pack2bf(acc[mm][nb][2], acc[mm][nb][3]);
      }
    }
    __syncthreads();
    const int bb = m0 >> 11, s0 = m0 & 2047;
#pragma unroll
    for (int i = 0; i < 4; ++i) {
      int id = i * 256 + tid;          // 1024 chunks: 64 rows x 16 chunks
      int row = id >> 4, ch = id & 15;
      int slot = ch ^ (row & 7);
      uint4 v = *reinterpret_cast<const uint4*>(vt + row * 128 + slot * 8);
      *reinterpret_cast<uint4*>(Vtg + ((size_t)(bb * NKVH + kvh) * HD + row) * SEQ + s0 + ch * 8) = v;
    }
  }
}

// ---------------- flash attention (R6-exact revert: measured 98.5us) -------
// grid: 896 blocks x 256 threads. XCD x owns (b,kvh): b=x>>1, kvh=x&1. 4 waves x 32q.
// R7 lesson: do NOT split Q across more blocks -- KV staging is a shared cost that
// replication doubles (98.5 -> 123us). This is the measured-best attn. Do not touch.
__global__ __launch_bounds__(256) void k_attn(
    const ushort_t* __restrict__ Qg,
    const ushort_t* __restrict__ Kg,
    const ushort_t* __restrict__ Vtg,
    ushort_t* __restrict__ attn) {
  __shared__ ushort_t kbuf[2][32 * 64];   // 32 keys x 64 d, 8-chunk XOR swizzle
  __shared__ ushort_t vbuf[2][64 * 32];   // 64 d x 32 tokens, 4-chunk swizzle (row>>1)
  __shared__ ushort_t pbuf[4][32 * 40];   // per-wave P: 32 q-rows x (32 keys + 8 pad)

  const int f = blockIdx.x;
  const int x = f & 7, s8 = f >> 3;     // s8: 0..111
  const int lh = s8 % 7;
  const int qt = s8 / 7;                // 0..15
  const int b = x >> 1, kvh = x & 1;
  const int h = kvh * 7 + lh;
  const int bh = b * NQH + h;
  const int tid = threadIdx.x;
  const int wave = tid >> 6, lane = tid & 63;
  const int l15 = lane & 15, quad = lane >> 4;
  const int q0 = qt * 128;

  bf16x8 qf[2][2];
#pragma unroll
  for (int qs = 0; qs < 2; ++qs) {
    const size_t qb = ((size_t)bh * SEQ + q0 + wave * 32 + qs * 16 + l15) * HD + quad * 8;
    qf[qs][0] = ldfrag(Qg + qb);
    qf[qs][1] = ldfrag(Qg + qb + 32);
  }

  const size_t kbase = (size_t)(b * NKVH + kvh) * SEQ * HD;
  const size_t vbase = (size_t)(b * NKVH + kvh) * HD * SEQ;

  // K: 32 rows x 8 chunks = 256 chunks (1/thread); dest linear, source inv-swizzled.
  const int krow = tid >> 3;
  const int kcs = (tid & 7) ^ (krow & 7);
  // V: 64 rows x 4 chunks = 256 chunks (1/thread); 4-slot swizzle keyed on row>>1.
  const int vrow = tid >> 2;
  const int vcs = (tid & 3) ^ ((vrow >> 1) & 3);
  const int sdst = wave * 512;          // wave-uniform LDS dest base (ushorts)

  // running global source pointers (bumped by one 32-token tile per stage)
  const ushort_t* kg = Kg + kbase + (size_t)krow * HD + kcs * 8;
  const ushort_t* vg = Vtg + vbase + (size_t)vrow * SEQ + vcs * 8;

  float l_part[2] = {0.f, 0.f};
  f32x4 o[2][4];
  const f32x4 z4 = {0.f, 0.f, 0.f, 0.f};
#pragma unroll
  for (int qs = 0; qs < 2; ++qs)
#pragma unroll
    for (int nb = 0; nb < 4; ++nb) o[qs][nb] = z4;

  ushort_t* pw = pbuf[wave];

  auto stage = [&](ushort_t* kb, ushort_t* vb) {
    async16(kg, kb + sdst);
    async16(vg, vb + sdst);
    kg += 32 * HD;
    vg += 32;
  };

  auto compute = [&](const ushort_t* kb, const ushort_t* vb) {
#pragma unroll
    for (int nb = 0; nb < 2; ++nb) {
      int row = nb * 16 + l15;
      int swz = row & 7;
      bf16x8 kf0 = ldfrag(kb + (row * 8 + (quad ^ swz)) * 8);
      bf16x8 kf1 = ldfrag(kb + (row * 8 + ((4 + quad) ^ swz)) * 8);
#pragma unroll
      for (int qs = 0; qs < 2; ++qs) {
        f32x4 t = z4;
        t = __builtin_amdgcn_mfma_f32_16x16x32_bf16(kf0, qf[qs][0], t, 0, 0, 0);
        t = __builtin_amdgcn_mfma_f32_16x16x32_bf16(kf1, qf[qs][1], t, 0, 0, 0);
        float p0 = __builtin_amdgcn_exp2f(t[0]);
        float p1 = __builtin_amdgcn_exp2f(t[1]);
        float p2 = __builtin_amdgcn_exp2f(t[2]);
        float p3 = __builtin_amdgcn_exp2f(t[3]);
        l_part[qs] += (p0 + p1) + (p2 + p3);
        uint2 d;
        d.x = cvtpk(p0, p1);
        d.y = cvtpk(p2, p3);
        *reinterpret_cast<uint2*>(pw + (qs * 16 + l15) * 40 + nb * 16 + quad * 4) = d;
      }
    }

    bf16x8 pf[2];
#pragma unroll
    for (int qs = 0; qs < 2; ++qs)
      pf[qs] = ldfrag(pw + (qs * 16 + l15) * 40 + quad * 8);
#pragma unroll
    for (int nb = 0; nb < 4; ++nb) {
      int row = nb * 16 + l15;
      bf16x8 vf = ldfrag(vb + row * 32 + ((quad ^ ((row >> 1) & 3)) * 8));
#pragma unroll
      for (int qs = 0; qs < 2; ++qs)
        o[qs][nb] = __builtin_amdgcn_mfma_f32_16x16x32_bf16(pf[qs], vf, o[qs][nb], 0, 0, 0);
    }
  };

  // prologue: stage tile 0, drain (also covers qf loads), barrier
  stage(kbuf[0], vbuf[0]);
  asm volatile("s_waitcnt vmcnt(0)" ::: "memory");
  __builtin_amdgcn_s_barrier();
  __builtin_amdgcn_sched_barrier(0);

  for (int jt = 0; jt < 62; jt += 2) {
    stage(kbuf[1], vbuf[1]);            // tile jt+1
    compute(kbuf[0], vbuf[0]);          // tile jt
    __builtin_amdgcn_sched_barrier(0);
    asm volatile("s_waitcnt vmcnt(0)" ::: "memory");
    __builtin_amdgcn_s_barrier();
    __builtin_amdgcn_sched_barrier(0);

    stage(kbuf[0], vbuf[0]);            // tile jt+2
    compute(kbuf[1], vbuf[1]);          // tile jt+1
    __builtin_amdgcn_sched_barrier(0);
    asm volatile("s_waitcnt vmcnt(0)" ::: "memory");
    __builtin_amdgcn_s_barrier();
    __builtin_amdgcn_sched_barrier(0);
  }
  // tiles 62 (in buf0) and 63
  stage(kbuf[1], vbuf[1]);              // tile 63
  compute(kbuf[0], vbuf[0]);            // tile 62
  __builtin_amdgcn_sched_barrier(0);
  asm volatile("s_waitcnt vmcnt(0)" ::: "memory");
  __builtin_amdgcn_s_barrier();
  __builtin_amdgcn_sched_barrier(0);
  compute(kbuf[1], vbuf[1]);            // tile 63

#pragma unroll
  for (int qs = 0; qs < 2; ++qs) {
    float s = l_part[qs];
    s += __shfl_xor(s, 16);
    s += __shfl_xor(s, 32);
    l_part[qs] = s;
  }

#pragma unroll
  for (int qs = 0; qs < 2; ++qs) {
    float il = 1.0f / l_part[qs];
#pragma unroll
    for (int r = 0; r < 4; ++r) {
      float inv = __shfl(il, quad * 4 + r);
      int qg = q0 + wave * 32 + qs * 16 + quad * 4 + r;
#pragma unroll
      for (int nb = 0; nb < 4; ++nb) {
        float val = o[qs][nb][r] * inv;
        attn[(size_t)(b * SEQ + qg) * (NQH * HD) + h * HD + nb * 16 + l15] = f2bf(val);
      }
    }
  }
}

// ---------------- output projection (R8: BK=32, 3-buffer counted-vmcnt pipeline) ------
// grid: 896 blocks (64 m-tiles x 14 n-sections), XCD-swizzled. Same loop as k_qkv.
__global__ __launch_bounds__(256) void k_oproj(
    const ushort_t* __restrict__ attn,
    const ushort_t* __restrict__ woT,
    float* __restrict__ out) {
  __shared__ ushort_t smem[18432];  // 3 bufs x 6144 (A 128x32 @0, B 64x32 @4096)

  const int f = blockIdx.x;
  const int x = f & 7, s8 = f >> 3;   // s8: 0..111
  const int n_sect = s8 % 14;
  const int mt = (s8 / 14) * 8 + x;   // 0..63
  const int n0 = n_sect * 64;
  const int m0 = mt * 128;
  const int tid = threadIdx.x;
  const int wave = tid >> 6, lane = tid & 63;
  const int l15 = lane & 15, quad = lane >> 4;
  const int c4 = quad ^ ((l15 >> 1) & 3);

  f32x4 acc[2][4];
  const f32x4 z4 = {0.f, 0.f, 0.f, 0.f};
#pragma unroll
  for (int mm = 0; mm < 2; ++mm)
#pragma unroll
    for (int nb = 0; nb < 4; ++nb) acc[mm][nb] = z4;

  const int cA1 = 256 + tid;
  const int rA0 = tid >> 2,  sA0 = (tid & 3) ^ ((rA0 >> 1) & 3);
  const int rA1 = cA1 >> 2,  sA1 = (cA1 & 3) ^ ((rA1 >> 1) & 3);
  const int rB  = tid >> 2,  sB  = (tid & 3) ^ ((rB >> 1) & 3);
  const ushort_t* pA0 = attn + (size_t)(m0 + rA0) * HIDDEN + sA0 * 8;
  const ushort_t* pA1 = attn + (size_t)(m0 + rA1) * HIDDEN + sA1 * 8;
  const ushort_t* pB  = woT + (size_t)(n0 + rB) * HIDDEN + sB * 8;
  const int dA0 = (wave * 64) * 8;
  const int dA1 = 2048 + (wave * 64) * 8;
  const int dB  = 4096 + (wave * 64) * 8;

  ushort_t* const b0 = smem;
  ushort_t* const b1 = smem + 6144;
  ushort_t* const b2 = smem + 12288;

  auto stage = [&](int off, ushort_t* buf) {
    async16(pA0 + off, buf + dA0);
    async16(pA1 + off, buf + dA1);
    async16(pB + off, buf + dB);
  };

  auto compute = [&](const ushort_t* buf) {
    bf16x8 af[2], bf[4];
#pragma unroll
    for (int mm = 0; mm < 2; ++mm)
      af[mm] = ldfrag(buf + (wave * 32 + mm * 16 + l15) * 32 + c4 * 8);
#pragma unroll
    for (int nb = 0; nb < 4; ++nb)
      bf[nb] = ldfrag(buf + 4096 + (nb * 16 + l15) * 32 + c4 * 8);
#pragma unroll
    for (int mm = 0; mm < 2; ++mm)
#pragma unroll
      for (int nb = 0; nb < 4; ++nb)
        acc[mm][nb] = __builtin_amdgcn_mfma_f32_16x16x32_bf16(af[mm], bf[nb], acc[mm][nb], 0, 0, 0);
  };

#define OPJ_SYNC() \
  __builtin_amdgcn_sched_barrier(0); \
  asm volatile("s_waitcnt vmcnt(3)" ::: "memory"); \
  __builtin_amdgcn_s_barrier(); \
  __builtin_amdgcn_sched_barrier(0);

  stage(0, b0);
  stage(32, b1);
  OPJ_SYNC();
  pA0 += 64; pA1 += 64; pB += 64;

  for (int i = 0; i < 8; ++i) {
    stage(0, b2);  compute(b0);  OPJ_SYNC();
    stage(32, b0); compute(b1);  OPJ_SYNC();
    stage(64, b1); compute(b2);  OPJ_SYNC();
    pA0 += 96; pA1 += 96; pB += 96;
  }
  stage(0, b2);  compute(b0);  OPJ_SYNC();
  stage(32, b0); compute(b1);  OPJ_SYNC();
  stage(32, b1); compute(b2);  OPJ_SYNC();
  compute(b0);                      // tile 27
#undef OPJ_SYNC

#pragma unroll
  for (int mm = 0; mm < 2; ++mm)
#pragma unroll
    for (int nb = 0; nb < 4; ++nb)
#pragma unroll
      for (int r = 0; r < 4; ++r)
        out[(size_t)(m0 + wave * 32 + mm * 16 + quad * 4 + r) * HIDDEN +
            n0 + nb * 16 + l15] = acc[mm][nb][r];
}

// ---------------- launch ----------------

extern "C" void kernel_launch(void* const* d_in, const int* in_sizes, int n_in,
                              void* d_out, int out_size, void* d_ws, size_t ws_size,
                              hipStream_t stream) {
  (void)in_sizes; (void)n_in; (void)out_size; (void)ws_size;
  const float* hidden = (const float*)d_in[0];
  const int* pos      = (const int*)d_in[1];
  const float* Wq     = (const float*)d_in[2];
  const float* Wk     = (const float*)d_in[3];
  const float* Wv     = (const float*)d_in[4];
  const float* Wo     = (const float*)d_in[5];
  float* out = (float*)d_out;

  char* ws = (char*)d_ws;
  ushort_t* hb   = (ushort_t*)(ws);               // [8192][896] bf16   14,680,064
  ushort_t* wT   = (ushort_t*)(ws + 14680064);    // [1152][896] bf16    2,064,384
  float2*   ctab = (float2*)  (ws + 16744448);    // [2048][32]            524,288
  ushort_t* Qg   = (ushort_t*)(ws + 17268736);    // [4][14][2048][64]  14,680,064
  ushort_t* Kg   = (ushort_t*)(ws + 31948800);    // [4][2][2048][64]    2,097,152
  ushort_t* Vtg  = (ushort_t*)(ws + 34045952);    // [4][2][64][2048]    2,097,152
  ushort_t* attn = (ushort_t*)(ws + 36143104);    // [8192][896] bf16   14,680,064
  ushort_t* woT  = (ushort_t*)(ws + 50823168);    // [896][896] bf16     1,605,632

  k_prep<<<9216, dim3(32, 8), 0, stream>>>(hidden, hb, Wq, Wk, Wv, Wo, wT, woT, ctab);
  k_qkv<<<1152, 256, 0, stream>>>(hb, wT, pos, ctab, Qg, Kg, Vtg);
  k_attn<<<896, 256, 0, stream>>>(Qg, Kg, Vtg, attn);
  k_oproj<<<896, 256, 0, stream>>>(attn, woT, out);
}

// Round 9
// 224.542 us; speedup vs baseline: 1.0962x; 1.0228x over previous
//
#include <hip/hip_runtime.h>
#include <hip/hip_bf16.h>
#include <math.h>

typedef unsigned short ushort_t;
typedef __bf16 bf16x8 __attribute__((ext_vector_type(8)));
typedef float f32x4 __attribute__((ext_vector_type(4)));

#define HIDDEN 896
#define NQH 14
#define NKVH 2
#define HD 64
#define SEQ 2048
#define NBATCH 4

__device__ inline ushort_t f2bf(float x) {
  union { float f; unsigned u; } c; c.f = x;
  unsigned r = c.u + 0x7FFFu + ((c.u >> 16) & 1u);
  return (ushort_t)(r >> 16);
}

__device__ inline unsigned pack2bf(float a, float b) {
  union { float f; unsigned u; } ca, cb; ca.f = a; cb.f = b;
  unsigned ua = ca.u + 0x8000u, ub = cb.u + 0x8000u;
  return __builtin_amdgcn_perm(ub, ua, 0x07060302);
}

// single-instruction pack: dst = {lo: bf16(a), hi: bf16(b)} (RNE)
__device__ inline unsigned cvtpk(float a, float b) {
  unsigned r;
  asm("v_cvt_pk_bf16_f32 %0, %1, %2" : "=v"(r) : "v"(a), "v"(b));
  return r;
}

__device__ inline bf16x8 ldfrag(const ushort_t* p) {
  return *reinterpret_cast<const bf16x8*>(p);
}

__device__ inline void async16(const ushort_t* g, ushort_t* l) {
  __builtin_amdgcn_global_load_lds(
      (const __attribute__((address_space(1))) void*)g,
      (__attribute__((address_space(3))) void*)l, 16, 0, 0);
}

// ---------------- prep ----------------

__device__ inline void transpose_sec(const float* __restrict__ in, ushort_t* __restrict__ out,
                                     int K, int N, int bx, int by) {
  __shared__ float tile[32][33];
  int k0 = by * 32, n0 = bx * 32;
  for (int r = threadIdx.y; r < 32; r += 8) {
    int k = k0 + r, n = n0 + threadIdx.x;
    tile[r][threadIdx.x] = (k < K && n < N) ? in[(size_t)k * N + n] : 0.f;
  }
  __syncthreads();
  for (int r = threadIdx.y; r < 32; r += 8) {
    int n = n0 + r, k = k0 + threadIdx.x;
    if (n < N && k < K) out[(size_t)n * K + k] = f2bf(tile[threadIdx.x][r]);
  }
}

__global__ void k_prep(const float* __restrict__ hidden, ushort_t* __restrict__ hb,
                       const float* __restrict__ Wq, const float* __restrict__ Wk,
                       const float* __restrict__ Wv, const float* __restrict__ Wo,
                       ushort_t* __restrict__ wT, ushort_t* __restrict__ woT,
                       float2* __restrict__ ctab) {
  const int blk = blockIdx.x;
  const int tid = threadIdx.y * 32 + threadIdx.x;
  if (blk < 7168) {
    int i = blk * 256 + tid;
    float4 v = reinterpret_cast<const float4*>(hidden)[i];
    ushort4 o;
    o.x = f2bf(v.x); o.y = f2bf(v.y); o.z = f2bf(v.z); o.w = f2bf(v.w);
    reinterpret_cast<ushort4*>(hb)[i] = o;
  } else if (blk < 7424) {
    int idx = (blk - 7168) * 256 + tid;
    int s = idx >> 5, dp = idx & 31;
    float inv = exp2f(-(float)dp * 0.41524101186092596f);
    float ang = (float)s * inv;
    float sn, cn;
    sincosf(ang, &sn, &cn);
    ctab[idx] = make_float2(cn, sn);
  } else if (blk < 8208) {
    int t = blk - 7424;
    transpose_sec(Wq, wT, 896, 896, t % 28, t / 28);
  } else if (blk < 8320) {
    int t = blk - 8208;
    transpose_sec(Wk, wT + (size_t)896 * 896, 896, 128, t % 4, t / 4);
  } else if (blk < 8432) {
    int t = blk - 8320;
    transpose_sec(Wv, wT + (size_t)1024 * 896, 896, 128, t % 4, t / 4);
  } else {
    int t = blk - 8432;
    transpose_sec(Wo, woT, 896, 896, t % 28, t / 28);
  }
}

// ---------------- QKV projection + RoPE (128x64 tiles, 32x64 wave-tile) ----------
// MEASURED-BEST (R6, total 222.1us). Session verdicts: 128x128 regressed (R1,
// block-count collapse); BK=32 counted-vmcnt 3-buffer regressed (R8, LDS cap
// 6->4 + 28 sync points with half the MFMA per phase). At shallow-K many-block
// shapes, co-resident-block TLP beats every pipeline restructure tried.
// grid: 1152 blocks 1D (64 m-tiles x 18 n-sections), XCD-swizzled.
// sect 0..13 = Q head; 14..15 = K kvh; 16..17 = V kvh.
__global__ __launch_bounds__(256) void k_qkv(
    const ushort_t* __restrict__ hb,
    const ushort_t* __restrict__ wT,
    const int* __restrict__ pos_ids,
    const float2* __restrict__ ctab,
    ushort_t* __restrict__ Qg,
    ushort_t* __restrict__ Kg,
    ushort_t* __restrict__ Vtg) {
  __shared__ ushort_t smem[12288];   // sa [0,8192) 128x64, sbb [8192,12288) 64x64
  ushort_t* sa = smem;
  ushort_t* sbb = smem + 8192;

  const int f = blockIdx.x;
  const int x = f & 7, s8 = f >> 3;       // s8: 0..143
  const int sect = s8 % 18;
  const int mt = (s8 / 18) * 8 + x;       // 0..63
  const int nt0 = sect * 64;
  const int m0 = mt * 128;
  const int tid = threadIdx.x;
  const int wave = tid >> 6, lane = tid & 63;
  const int l15 = lane & 15, quad = lane >> 4;
  const int sw = l15 & 7;

  f32x4 acc[2][4];
  const f32x4 z4 = {0.f, 0.f, 0.f, 0.f};
#pragma unroll
  for (int mm = 0; mm < 2; ++mm)
#pragma unroll
    for (int nb = 0; nb < 4; ++nb) acc[mm][nb] = z4;

  for (int kt = 0; kt < 14; ++kt) {
    const int k0 = kt * 64;
    __syncthreads();
#pragma unroll
    for (int i = 0; i < 4; ++i) {
      int id = i * 256 + tid;
      int row = id >> 3;                  // 0..127
      int cs = (id & 7) ^ (row & 7);
      async16(hb + (size_t)(m0 + row) * HIDDEN + k0 + cs * 8, sa + (i * 256 + wave * 64) * 8);
    }
#pragma unroll
    for (int i = 0; i < 2; ++i) {
      int id = i * 256 + tid;
      int row = id >> 3;                  // 0..63
      int cs = (id & 7) ^ (row & 7);
      async16(wT + (size_t)(nt0 + row) * HIDDEN + k0 + cs * 8, sbb + (i * 256 + wave * 64) * 8);
    }
    __syncthreads();
#pragma unroll
    for (int kc = 0; kc < 2; ++kc) {
      int c = kc * 4 + quad;
      bf16x8 af[2], bf[4];
#pragma unroll
      for (int mm = 0; mm < 2; ++mm)
        af[mm] = ldfrag(sa + ((wave * 32 + mm * 16 + l15) * 8 + (c ^ sw)) * 8);
#pragma unroll
      for (int nb = 0; nb < 4; ++nb)
        bf[nb] = ldfrag(sbb + ((nb * 16 + l15) * 8 + (c ^ sw)) * 8);
#pragma unroll
      for (int mm = 0; mm < 2; ++mm)
#pragma unroll
        for (int nb = 0; nb < 4; ++nb)
          acc[mm][nb] = __builtin_amdgcn_mfma_f32_16x16x32_bf16(af[mm], bf[nb], acc[mm][nb], 0, 0, 0);
    }
  }

  if (sect < 16) {
    const bool isQ = sect < 14;
    const float csc = isQ ? 0.125f * 1.4426950408889634f : 1.0f;
    ushort_t* dst = isQ ? Qg : Kg;
    const int nheads = isQ ? NQH : NKVH;
    const int hh = isQ ? sect : sect - 14;
#pragma unroll
    for (int mm = 0; mm < 2; ++mm) {
#pragma unroll
      for (int r = 0; r < 4; ++r) {
        int token = m0 + wave * 32 + mm * 16 + quad * 4 + r;
        int b = token >> 11, s = token & 2047;
        int pos = pos_ids[token];
        size_t base = ((size_t)(b * nheads + hh) * SEQ + s) * HD;
#pragma unroll
        for (int nb = 0; nb < 2; ++nb) {
          float2 cs = ctab[pos * 32 + nb * 16 + l15];
          float x0 = acc[mm][nb][r];
          float x1 = acc[mm][nb + 2][r];
          float y0 = (x0 * cs.x - x1 * cs.y) * csc;
          float y1 = (x1 * cs.x + x0 * cs.y) * csc;
          dst[base + nb * 16 + l15]      = f2bf(y0);
          dst[base + nb * 16 + l15 + 32] = f2bf(y1);
        }
      }
    }
  } else {
    const int kvh = sect - 16;
    __syncthreads();
    ushort_t* vt = smem;  // 64 d-rows x 128 tokens = 8192 ushorts (16KB of 24KB)
#pragma unroll
    for (int mm = 0; mm < 2; ++mm) {
      int tl = wave * 32 + mm * 16 + quad * 4;   // token base (r=0..3), 0..124
      int chunk = tl >> 3, ofs = tl & 7;         // chunk 0..15, ofs = 0 or 4
#pragma unroll
      for (int nb = 0; nb < 4; ++nb) {
        int row = nb * 16 + l15;                 // d
        int slot = chunk ^ (row & 7);            // XOR low 3 bits of 4-bit chunk
        ushort_t* p = vt + row * 128 + slot * 8 + ofs;
        *reinterpret_cast<unsigned*>(p)     = pack2bf(acc[mm][nb][0], acc[mm][nb][1]);
        *reinterpret_cast<unsigned*>(p + 2) = pack2bf(acc[mm][nb][2], acc[mm][nb][3]);
      }
    }
    __syncthreads();
    const int bb = m0 >> 11, s0 = m0 & 2047;
#pragma unroll
    for (int i = 0; i < 4; ++i) {
      int id = i * 256 + tid;          // 1024 chunks: 64 rows x 16 chunks
      int row = id >> 4, ch = id & 15;
      int slot = ch ^ (row & 7);
      uint4 v = *reinterpret_cast<const uint4*>(vt + row * 128 + slot * 8);
      *reinterpret_cast<uint4*>(Vtg + ((size_t)(bb * NKVH + kvh) * HD + row) * SEQ + s0 + ch * 8) = v;
    }
  }
}

// ---------------- flash attention (R6-exact: measured best 96.7-98.5us) -------
// grid: 896 blocks x 256 threads. XCD x owns (b,kvh): b=x>>1, kvh=x&1. 4 waves x 32q.
// Session verdicts: KBLK=64 dbuf collapsed occupancy (R2); Q-split doubles shared
// KV staging cost (R7, 98->123us); counted-vmcnt/pipeline variants all regress.
// KBLK=32 dbuf at constant occupancy + literal buffers + cvt_pk is the optimum
// found. Do not restructure.
__global__ __launch_bounds__(256) void k_attn(
    const ushort_t* __restrict__ Qg,
    const ushort_t* __restrict__ Kg,
    const ushort_t* __restrict__ Vtg,
    ushort_t* __restrict__ attn) {
  __shared__ ushort_t kbuf[2][32 * 64];   // 32 keys x 64 d, 8-chunk XOR swizzle
  __shared__ ushort_t vbuf[2][64 * 32];   // 64 d x 32 tokens, 4-chunk swizzle (row>>1)
  __shared__ ushort_t pbuf[4][32 * 40];   // per-wave P: 32 q-rows x (32 keys + 8 pad)

  const int f = blockIdx.x;
  const int x = f & 7, s8 = f >> 3;     // s8: 0..111
  const int lh = s8 % 7;
  const int qt = s8 / 7;                // 0..15
  const int b = x >> 1, kvh = x & 1;
  const int h = kvh * 7 + lh;
  const int bh = b * NQH + h;
  const int tid = threadIdx.x;
  const int wave = tid >> 6, lane = tid & 63;
  const int l15 = lane & 15, quad = lane >> 4;
  const int q0 = qt * 128;

  bf16x8 qf[2][2];
#pragma unroll
  for (int qs = 0; qs < 2; ++qs) {
    const size_t qb = ((size_t)bh * SEQ + q0 + wave * 32 + qs * 16 + l15) * HD + quad * 8;
    qf[qs][0] = ldfrag(Qg + qb);
    qf[qs][1] = ldfrag(Qg + qb + 32);
  }

  const size_t kbase = (size_t)(b * NKVH + kvh) * SEQ * HD;
  const size_t vbase = (size_t)(b * NKVH + kvh) * HD * SEQ;

  // K: 32 rows x 8 chunks = 256 chunks (1/thread); dest linear, source inv-swizzled.
  const int krow = tid >> 3;
  const int kcs = (tid & 7) ^ (krow & 7);
  // V: 64 rows x 4 chunks = 256 chunks (1/thread); 4-slot swizzle keyed on row>>1.
  const int vrow = tid >> 2;
  const int vcs = (tid & 3) ^ ((vrow >> 1) & 3);
  const int sdst = wave * 512;          // wave-uniform LDS dest base (ushorts)

  // running global source pointers (bumped by one 32-token tile per stage)
  const ushort_t* kg = Kg + kbase + (size_t)krow * HD + kcs * 8;
  const ushort_t* vg = Vtg + vbase + (size_t)vrow * SEQ + vcs * 8;

  float l_part[2] = {0.f, 0.f};
  f32x4 o[2][4];
  const f32x4 z4 = {0.f, 0.f, 0.f, 0.f};
#pragma unroll
  for (int qs = 0; qs < 2; ++qs)
#pragma unroll
    for (int nb = 0; nb < 4; ++nb) o[qs][nb] = z4;

  ushort_t* pw = pbuf[wave];

  auto stage = [&](ushort_t* kb, ushort_t* vb) {
    async16(kg, kb + sdst);
    async16(vg, vb + sdst);
    kg += 32 * HD;
    vg += 32;
  };

  auto compute = [&](const ushort_t* kb, const ushort_t* vb) {
#pragma unroll
    for (int nb = 0; nb < 2; ++nb) {
      int row = nb * 16 + l15;
      int swz = row & 7;
      bf16x8 kf0 = ldfrag(kb + (row * 8 + (quad ^ swz)) * 8);
      bf16x8 kf1 = ldfrag(kb + (row * 8 + ((4 + quad) ^ swz)) * 8);
#pragma unroll
      for (int qs = 0; qs < 2; ++qs) {
        f32x4 t = z4;
        t = __builtin_amdgcn_mfma_f32_16x16x32_bf16(kf0, qf[qs][0], t, 0, 0, 0);
        t = __builtin_amdgcn_mfma_f32_16x16x32_bf16(kf1, qf[qs][1], t, 0, 0, 0);
        float p0 = __builtin_amdgcn_exp2f(t[0]);
        float p1 = __builtin_amdgcn_exp2f(t[1]);
        float p2 = __builtin_amdgcn_exp2f(t[2]);
        float p3 = __builtin_amdgcn_exp2f(t[3]);
        l_part[qs] += (p0 + p1) + (p2 + p3);
        uint2 d;
        d.x = cvtpk(p0, p1);
        d.y = cvtpk(p2, p3);
        *reinterpret_cast<uint2*>(pw + (qs * 16 + l15) * 40 + nb * 16 + quad * 4) = d;
      }
    }

    bf16x8 pf[2];
#pragma unroll
    for (int qs = 0; qs < 2; ++qs)
      pf[qs] = ldfrag(pw + (qs * 16 + l15) * 40 + quad * 8);
#pragma unroll
    for (int nb = 0; nb < 4; ++nb) {
      int row = nb * 16 + l15;
      bf16x8 vf = ldfrag(vb + row * 32 + ((quad ^ ((row >> 1) & 3)) * 8));
#pragma unroll
      for (int qs = 0; qs < 2; ++qs)
        o[qs][nb] = __builtin_amdgcn_mfma_f32_16x16x32_bf16(pf[qs], vf, o[qs][nb], 0, 0, 0);
    }
  };

  // prologue: stage tile 0, drain (also covers qf loads), barrier
  stage(kbuf[0], vbuf[0]);
  asm volatile("s_waitcnt vmcnt(0)" ::: "memory");
  __builtin_amdgcn_s_barrier();
  __builtin_amdgcn_sched_barrier(0);

  for (int jt = 0; jt < 62; jt += 2) {
    stage(kbuf[1], vbuf[1]);            // tile jt+1
    compute(kbuf[0], vbuf[0]);          // tile jt
    __builtin_amdgcn_sched_barrier(0);
    asm volatile("s_waitcnt vmcnt(0)" ::: "memory");
    __builtin_amdgcn_s_barrier();
    __builtin_amdgcn_sched_barrier(0);

    stage(kbuf[0], vbuf[0]);            // tile jt+2
    compute(kbuf[1], vbuf[1]);          // tile jt+1
    __builtin_amdgcn_sched_barrier(0);
    asm volatile("s_waitcnt vmcnt(0)" ::: "memory");
    __builtin_amdgcn_s_barrier();
    __builtin_amdgcn_sched_barrier(0);
  }
  // tiles 62 (in buf0) and 63
  stage(kbuf[1], vbuf[1]);              // tile 63
  compute(kbuf[0], vbuf[0]);            // tile 62
  __builtin_amdgcn_sched_barrier(0);
  asm volatile("s_waitcnt vmcnt(0)" ::: "memory");
  __builtin_amdgcn_s_barrier();
  __builtin_amdgcn_sched_barrier(0);
  compute(kbuf[1], vbuf[1]);            // tile 63

#pragma unroll
  for (int qs = 0; qs < 2; ++qs) {
    float s = l_part[qs];
    s += __shfl_xor(s, 16);
    s += __shfl_xor(s, 32);
    l_part[qs] = s;
  }

#pragma unroll
  for (int qs = 0; qs < 2; ++qs) {
    float il = 1.0f / l_part[qs];
#pragma unroll
    for (int r = 0; r < 4; ++r) {
      float inv = __shfl(il, quad * 4 + r);
      int qg = q0 + wave * 32 + qs * 16 + quad * 4 + r;
#pragma unroll
      for (int nb = 0; nb < 4; ++nb) {
        float val = o[qs][nb][r] * inv;
        attn[(size_t)(b * SEQ + qg) * (NQH * HD) + h * HD + nb * 16 + l15] = f2bf(val);
      }
    }
  }
}

// ---------------- output projection (128x64 tiles, 32x64 wave-tile) ----------------
// MEASURED-BEST (R6). grid: 896 blocks (64 m-tiles x 14 n-sections), XCD-swizzled.
__global__ __launch_bounds__(256) void k_oproj(
    const ushort_t* __restrict__ attn,
    const ushort_t* __restrict__ woT,
    float* __restrict__ out) {
  __shared__ ushort_t smem[12288];
  ushort_t* sa = smem;
  ushort_t* sbb = smem + 8192;

  const int f = blockIdx.x;
  const int x = f & 7, s8 = f >> 3;   // s8: 0..111
  const int n_sect = s8 % 14;
  const int mt = (s8 / 14) * 8 + x;   // 0..63
  const int n0 = n_sect * 64;
  const int m0 = mt * 128;
  const int tid = threadIdx.x;
  const int wave = tid >> 6, lane = tid & 63;
  const int l15 = lane & 15, quad = lane >> 4;
  const int sw = l15 & 7;

  f32x4 acc[2][4];
  const f32x4 z4 = {0.f, 0.f, 0.f, 0.f};
#pragma unroll
  for (int mm = 0; mm < 2; ++mm)
#pragma unroll
    for (int nb = 0; nb < 4; ++nb) acc[mm][nb] = z4;

  for (int kt = 0; kt < 14; ++kt) {
    const int k0 = kt * 64;
    __syncthreads();
#pragma unroll
    for (int i = 0; i < 4; ++i) {
      int id = i * 256 + tid;
      int row = id >> 3;                // 0..127
      int cs = (id & 7) ^ (row & 7);
      async16(attn + (size_t)(m0 + row) * HIDDEN + k0 + cs * 8, sa + (i * 256 + wave * 64) * 8);
    }
#pragma unroll
    for (int i = 0; i < 2; ++i) {
      int id = i * 256 + tid;
      int row = id >> 3;                // 0..63
      int cs = (id & 7) ^ (row & 7);
      async16(woT + (size_t)(n0 + row) * HIDDEN + k0 + cs * 8, sbb + (i * 256 + wave * 64) * 8);
    }
    __syncthreads();
#pragma unroll
    for (int kc = 0; kc < 2; ++kc) {
      int c = kc * 4 + quad;
      bf16x8 af[2], bf[4];
#pragma unroll
      for (int mm = 0; mm < 2; ++mm)
        af[mm] = ldfrag(sa + ((wave * 32 + mm * 16 + l15) * 8 + (c ^ sw)) * 8);
#pragma unroll
      for (int nb = 0; nb < 4; ++nb)
        bf[nb] = ldfrag(sbb + ((nb * 16 + l15) * 8 + (c ^ sw)) * 8);
#pragma unroll
      for (int mm = 0; mm < 2; ++mm)
#pragma unroll
        for (int nb = 0; nb < 4; ++nb)
          acc[mm][nb] = __builtin_amdgcn_mfma_f32_16x16x32_bf16(af[mm], bf[nb], acc[mm][nb], 0, 0, 0);
    }
  }

#pragma unroll
  for (int mm = 0; mm < 2; ++mm)
#pragma unroll
    for (int nb = 0; nb < 4; ++nb)
#pragma unroll
      for (int r = 0; r < 4; ++r)
        out[(size_t)(m0 + wave * 32 + mm * 16 + quad * 4 + r) * HIDDEN +
            n0 + nb * 16 + l15] = acc[mm][nb][r];
}

// ---------------- launch ----------------

extern "C" void kernel_launch(void* const* d_in, const int* in_sizes, int n_in,
                              void* d_out, int out_size, void* d_ws, size_t ws_size,
                              hipStream_t stream) {
  (void)in_sizes; (void)n_in; (void)out_size; (void)ws_size;
  const float* hidden = (const float*)d_in[0];
  const int* pos      = (const int*)d_in[1];
  const float* Wq     = (const float*)d_in[2];
  const float* Wk     = (const float*)d_in[3];
  const float* Wv     = (const float*)d_in[4];
  const float* Wo     = (const float*)d_in[5];
  float* out = (float*)d_out;

  char* ws = (char*)d_ws;
  ushort_t* hb   = (ushort_t*)(ws);               // [8192][896] bf16   14,680,064
  ushort_t* wT   = (ushort_t*)(ws + 14680064);    // [1152][896] bf16    2,064,384
  float2*   ctab = (float2*)  (ws + 16744448);    // [2048][32]            524,288
  ushort_t* Qg   = (ushort_t*)(ws + 17268736);    // [4][14][2048][64]  14,680,064
  ushort_t* Kg   = (ushort_t*)(ws + 31948800);    // [4][2][2048][64]    2,097,152
  ushort_t* Vtg  = (ushort_t*)(ws + 34045952);    // [4][2][64][2048]    2,097,152
  ushort_t* attn = (ushort_t*)(ws + 36143104);    // [8192][896] bf16   14,680,064
  ushort_t* woT  = (ushort_t*)(ws + 50823168);    // [896][896] bf16     1,605,632

  k_prep<<<9216, dim3(32, 8), 0, stream>>>(hidden, hb, Wq, Wk, Wv, Wo, wT, woT, ctab);
  k_qkv<<<1152, 256, 0, stream>>>(hb, wT, pos, ctab, Qg, Kg, Vtg);
  k_attn<<<896, 256, 0, stream>>>(Qg, Kg, Vtg, attn);
  k_oproj<<<896, 256, 0, stream>>>(attn, woT, out);
}

// Round 11
// 223.490 us; speedup vs baseline: 1.1013x; 1.0047x over previous
//
#include <hip/hip_runtime.h>
#include <hip/hip_bf16.h>
#include <math.h>

typedef unsigned short ushort_t;
typedef __bf16 bf16x8 __attribute__((ext_vector_type(8)));
typedef float f32x4 __attribute__((ext_vector_type(4)));

#define HIDDEN 896
#define NQH 14
#define NKVH 2
#define HD 64
#define SEQ 2048
#define NBATCH 4

__device__ inline ushort_t f2bf(float x) {
  union { float f; unsigned u; } c; c.f = x;
  unsigned r = c.u + 0x7FFFu + ((c.u >> 16) & 1u);
  return (ushort_t)(r >> 16);
}

__device__ inline unsigned pack2bf(float a, float b) {
  union { float f; unsigned u; } ca, cb; ca.f = a; cb.f = b;
  unsigned ua = ca.u + 0x8000u, ub = cb.u + 0x8000u;
  return __builtin_amdgcn_perm(ub, ua, 0x07060302);
}

// single-instruction pack: dst = {lo: bf16(a), hi: bf16(b)} (RNE)
__device__ inline unsigned cvtpk(float a, float b) {
  unsigned r;
  asm("v_cvt_pk_bf16_f32 %0, %1, %2" : "=v"(r) : "v"(a), "v"(b));
  return r;
}

__device__ inline bf16x8 ldfrag(const ushort_t* p) {
  return *reinterpret_cast<const bf16x8*>(p);
}

__device__ inline void async16(const ushort_t* g, ushort_t* l) {
  __builtin_amdgcn_global_load_lds(
      (const __attribute__((address_space(1))) void*)g,
      (__attribute__((address_space(3))) void*)l, 16, 0, 0);
}

// ---------------- prep ----------------

__device__ inline void transpose_sec(const float* __restrict__ in, ushort_t* __restrict__ out,
                                     int K, int N, int bx, int by) {
  __shared__ float tile[32][33];
  int k0 = by * 32, n0 = bx * 32;
  for (int r = threadIdx.y; r < 32; r += 8) {
    int k = k0 + r, n = n0 + threadIdx.x;
    tile[r][threadIdx.x] = (k < K && n < N) ? in[(size_t)k * N + n] : 0.f;
  }
  __syncthreads();
  for (int r = threadIdx.y; r < 32; r += 8) {
    int n = n0 + r, k = k0 + threadIdx.x;
    if (n < N && k < K) out[(size_t)n * K + k] = f2bf(tile[threadIdx.x][r]);
  }
}

__global__ void k_prep(const float* __restrict__ hidden, ushort_t* __restrict__ hb,
                       const float* __restrict__ Wq, const float* __restrict__ Wk,
                       const float* __restrict__ Wv, const float* __restrict__ Wo,
                       ushort_t* __restrict__ wT, ushort_t* __restrict__ woT,
                       float2* __restrict__ ctab) {
  const int blk = blockIdx.x;
  const int tid = threadIdx.y * 32 + threadIdx.x;
  if (blk < 7168) {
    int i = blk * 256 + tid;
    float4 v = reinterpret_cast<const float4*>(hidden)[i];
    ushort4 o;
    o.x = f2bf(v.x); o.y = f2bf(v.y); o.z = f2bf(v.z); o.w = f2bf(v.w);
    reinterpret_cast<ushort4*>(hb)[i] = o;
  } else if (blk < 7424) {
    int idx = (blk - 7168) * 256 + tid;
    int s = idx >> 5, dp = idx & 31;
    float inv = exp2f(-(float)dp * 0.41524101186092596f);
    float ang = (float)s * inv;
    float sn, cn;
    sincosf(ang, &sn, &cn);
    ctab[idx] = make_float2(cn, sn);
  } else if (blk < 8208) {
    int t = blk - 7424;
    transpose_sec(Wq, wT, 896, 896, t % 28, t / 28);
  } else if (blk < 8320) {
    int t = blk - 8208;
    transpose_sec(Wk, wT + (size_t)896 * 896, 896, 128, t % 4, t / 4);
  } else if (blk < 8432) {
    int t = blk - 8320;
    transpose_sec(Wv, wT + (size_t)1024 * 896, 896, 128, t % 4, t / 4);
  } else {
    int t = blk - 8432;
    transpose_sec(Wo, woT, 896, 896, t % 28, t / 28);
  }
}

// ---------------- QKV projection + RoPE (128x64 tiles, 32x64 wave-tile) ----------
// MEASURED-BEST (R6/R9, total 222.1-224.5us). Session verdicts: 128x128 regressed
// (R1, block-count collapse); BK=32 counted-vmcnt 3-buffer regressed (R8, LDS cap
// 6->4 + 28 sync points with half the MFMA per phase). At shallow-K many-block
// shapes, co-resident-block TLP beats every pipeline restructure tried.
// grid: 1152 blocks 1D (64 m-tiles x 18 n-sections), XCD-swizzled.
// sect 0..13 = Q head; 14..15 = K kvh; 16..17 = V kvh.
__global__ __launch_bounds__(256) void k_qkv(
    const ushort_t* __restrict__ hb,
    const ushort_t* __restrict__ wT,
    const int* __restrict__ pos_ids,
    const float2* __restrict__ ctab,
    ushort_t* __restrict__ Qg,
    ushort_t* __restrict__ Kg,
    ushort_t* __restrict__ Vtg) {
  __shared__ ushort_t smem[12288];   // sa [0,8192) 128x64, sbb [8192,12288) 64x64
  ushort_t* sa = smem;
  ushort_t* sbb = smem + 8192;

  const int f = blockIdx.x;
  const int x = f & 7, s8 = f >> 3;       // s8: 0..143
  const int sect = s8 % 18;
  const int mt = (s8 / 18) * 8 + x;       // 0..63
  const int nt0 = sect * 64;
  const int m0 = mt * 128;
  const int tid = threadIdx.x;
  const int wave = tid >> 6, lane = tid & 63;
  const int l15 = lane & 15, quad = lane >> 4;
  const int sw = l15 & 7;

  f32x4 acc[2][4];
  const f32x4 z4 = {0.f, 0.f, 0.f, 0.f};
#pragma unroll
  for (int mm = 0; mm < 2; ++mm)
#pragma unroll
    for (int nb = 0; nb < 4; ++nb) acc[mm][nb] = z4;

  for (int kt = 0; kt < 14; ++kt) {
    const int k0 = kt * 64;
    __syncthreads();
#pragma unroll
    for (int i = 0; i < 4; ++i) {
      int id = i * 256 + tid;
      int row = id >> 3;                  // 0..127
      int cs = (id & 7) ^ (row & 7);
      async16(hb + (size_t)(m0 + row) * HIDDEN + k0 + cs * 8, sa + (i * 256 + wave * 64) * 8);
    }
#pragma unroll
    for (int i = 0; i < 2; ++i) {
      int id = i * 256 + tid;
      int row = id >> 3;                  // 0..63
      int cs = (id & 7) ^ (row & 7);
      async16(wT + (size_t)(nt0 + row) * HIDDEN + k0 + cs * 8, sbb + (i * 256 + wave * 64) * 8);
    }
    __syncthreads();
#pragma unroll
    for (int kc = 0; kc < 2; ++kc) {
      int c = kc * 4 + quad;
      bf16x8 af[2], bf[4];
#pragma unroll
      for (int mm = 0; mm < 2; ++mm)
        af[mm] = ldfrag(sa + ((wave * 32 + mm * 16 + l15) * 8 + (c ^ sw)) * 8);
#pragma unroll
      for (int nb = 0; nb < 4; ++nb)
        bf[nb] = ldfrag(sbb + ((nb * 16 + l15) * 8 + (c ^ sw)) * 8);
#pragma unroll
      for (int mm = 0; mm < 2; ++mm)
#pragma unroll
        for (int nb = 0; nb < 4; ++nb)
          acc[mm][nb] = __builtin_amdgcn_mfma_f32_16x16x32_bf16(af[mm], bf[nb], acc[mm][nb], 0, 0, 0);
    }
  }

  if (sect < 16) {
    const bool isQ = sect < 14;
    const float csc = isQ ? 0.125f * 1.4426950408889634f : 1.0f;
    ushort_t* dst = isQ ? Qg : Kg;
    const int nheads = isQ ? NQH : NKVH;
    const int hh = isQ ? sect : sect - 14;
#pragma unroll
    for (int mm = 0; mm < 2; ++mm) {
#pragma unroll
      for (int r = 0; r < 4; ++r) {
        int token = m0 + wave * 32 + mm * 16 + quad * 4 + r;
        int b = token >> 11, s = token & 2047;
        int pos = pos_ids[token];
        size_t base = ((size_t)(b * nheads + hh) * SEQ + s) * HD;
#pragma unroll
        for (int nb = 0; nb < 2; ++nb) {
          float2 cs = ctab[pos * 32 + nb * 16 + l15];
          float x0 = acc[mm][nb][r];
          float x1 = acc[mm][nb + 2][r];
          float y0 = (x0 * cs.x - x1 * cs.y) * csc;
          float y1 = (x1 * cs.x + x0 * cs.y) * csc;
          dst[base + nb * 16 + l15]      = f2bf(y0);
          dst[base + nb * 16 + l15 + 32] = f2bf(y1);
        }
      }
    }
  } else {
    const int kvh = sect - 16;
    __syncthreads();
    ushort_t* vt = smem;  // 64 d-rows x 128 tokens = 8192 ushorts (16KB of 24KB)
#pragma unroll
    for (int mm = 0; mm < 2; ++mm) {
      int tl = wave * 32 + mm * 16 + quad * 4;   // token base (r=0..3), 0..124
      int chunk = tl >> 3, ofs = tl & 7;         // chunk 0..15, ofs = 0 or 4
#pragma unroll
      for (int nb = 0; nb < 4; ++nb) {
        int row = nb * 16 + l15;                 // d
        int slot = chunk ^ (row & 7);            // XOR low 3 bits of 4-bit chunk
        ushort_t* p = vt + row * 128 + slot * 8 + ofs;
        *reinterpret_cast<unsigned*>(p)     = pack2bf(acc[mm][nb][0], acc[mm][nb][1]);
        *reinterpret_cast<unsigned*>(p + 2) = pack2bf(acc[mm][nb][2], acc[mm][nb][3]);
      }
    }
    __syncthreads();
    const int bb = m0 >> 11, s0 = m0 & 2047;
#pragma unroll
    for (int i = 0; i < 4; ++i) {
      int id = i * 256 + tid;          // 1024 chunks: 64 rows x 16 chunks
      int row = id >> 4, ch = id & 15;
      int slot = ch ^ (row & 7);
      uint4 v = *reinterpret_cast<const uint4*>(vt + row * 128 + slot * 8);
      *reinterpret_cast<uint4*>(Vtg + ((size_t)(bb * NKVH + kvh) * HD + row) * SEQ + s0 + ch * 8) = v;
    }
  }
}

// ---------------- flash attention (R6-exact: measured best 96.7-98.5us) -------
// grid: 896 blocks x 256 threads. XCD x owns (b,kvh): b=x>>1, kvh=x&1. 4 waves x 32q.
// Session verdicts: KBLK=64 dbuf collapsed occupancy (R2); Q-split doubles shared
// KV staging cost (R7, 98->123us); counted-vmcnt/pipeline variants regress (R8);
// 2-wave x 64q restructure races nondeterministically (R10). This 4-wave KBLK=32
// dbuf at constant occupancy + literal buffers + cvt_pk is the verified optimum.
// Do not restructure.
__global__ __launch_bounds__(256) void k_attn(
    const ushort_t* __restrict__ Qg,
    const ushort_t* __restrict__ Kg,
    const ushort_t* __restrict__ Vtg,
    ushort_t* __restrict__ attn) {
  __shared__ ushort_t kbuf[2][32 * 64];   // 32 keys x 64 d, 8-chunk XOR swizzle
  __shared__ ushort_t vbuf[2][64 * 32];   // 64 d x 32 tokens, 4-chunk swizzle (row>>1)
  __shared__ ushort_t pbuf[4][32 * 40];   // per-wave P: 32 q-rows x (32 keys + 8 pad)

  const int f = blockIdx.x;
  const int x = f & 7, s8 = f >> 3;     // s8: 0..111
  const int lh = s8 % 7;
  const int qt = s8 / 7;                // 0..15
  const int b = x >> 1, kvh = x & 1;
  const int h = kvh * 7 + lh;
  const int bh = b * NQH + h;
  const int tid = threadIdx.x;
  const int wave = tid >> 6, lane = tid & 63;
  const int l15 = lane & 15, quad = lane >> 4;
  const int q0 = qt * 128;

  bf16x8 qf[2][2];
#pragma unroll
  for (int qs = 0; qs < 2; ++qs) {
    const size_t qb = ((size_t)bh * SEQ + q0 + wave * 32 + qs * 16 + l15) * HD + quad * 8;
    qf[qs][0] = ldfrag(Qg + qb);
    qf[qs][1] = ldfrag(Qg + qb + 32);
  }

  const size_t kbase = (size_t)(b * NKVH + kvh) * SEQ * HD;
  const size_t vbase = (size_t)(b * NKVH + kvh) * HD * SEQ;

  // K: 32 rows x 8 chunks = 256 chunks (1/thread); dest linear, source inv-swizzled.
  const int krow = tid >> 3;
  const int kcs = (tid & 7) ^ (krow & 7);
  // V: 64 rows x 4 chunks = 256 chunks (1/thread); 4-slot swizzle keyed on row>>1.
  const int vrow = tid >> 2;
  const int vcs = (tid & 3) ^ ((vrow >> 1) & 3);
  const int sdst = wave * 512;          // wave-uniform LDS dest base (ushorts)

  // running global source pointers (bumped by one 32-token tile per stage)
  const ushort_t* kg = Kg + kbase + (size_t)krow * HD + kcs * 8;
  const ushort_t* vg = Vtg + vbase + (size_t)vrow * SEQ + vcs * 8;

  float l_part[2] = {0.f, 0.f};
  f32x4 o[2][4];
  const f32x4 z4 = {0.f, 0.f, 0.f, 0.f};
#pragma unroll
  for (int qs = 0; qs < 2; ++qs)
#pragma unroll
    for (int nb = 0; nb < 4; ++nb) o[qs][nb] = z4;

  ushort_t* pw = pbuf[wave];

  auto stage = [&](ushort_t* kb, ushort_t* vb) {
    async16(kg, kb + sdst);
    async16(vg, vb + sdst);
    kg += 32 * HD;
    vg += 32;
  };

  auto compute = [&](const ushort_t* kb, const ushort_t* vb) {
#pragma unroll
    for (int nb = 0; nb < 2; ++nb) {
      int row = nb * 16 + l15;
      int swz = row & 7;
      bf16x8 kf0 = ldfrag(kb + (row * 8 + (quad ^ swz)) * 8);
      bf16x8 kf1 = ldfrag(kb + (row * 8 + ((4 + quad) ^ swz)) * 8);
#pragma unroll
      for (int qs = 0; qs < 2; ++qs) {
        f32x4 t = z4;
        t = __builtin_amdgcn_mfma_f32_16x16x32_bf16(kf0, qf[qs][0], t, 0, 0, 0);
        t = __builtin_amdgcn_mfma_f32_16x16x32_bf16(kf1, qf[qs][1], t, 0, 0, 0);
        float p0 = __builtin_amdgcn_exp2f(t[0]);
        float p1 = __builtin_amdgcn_exp2f(t[1]);
        float p2 = __builtin_amdgcn_exp2f(t[2]);
        float p3 = __builtin_amdgcn_exp2f(t[3]);
        l_part[qs] += (p0 + p1) + (p2 + p3);
        uint2 d;
        d.x = cvtpk(p0, p1);
        d.y = cvtpk(p2, p3);
        *reinterpret_cast<uint2*>(pw + (qs * 16 + l15) * 40 + nb * 16 + quad * 4) = d;
      }
    }

    bf16x8 pf[2];
#pragma unroll
    for (int qs = 0; qs < 2; ++qs)
      pf[qs] = ldfrag(pw + (qs * 16 + l15) * 40 + quad * 8);
#pragma unroll
    for (int nb = 0; nb < 4; ++nb) {
      int row = nb * 16 + l15;
      bf16x8 vf = ldfrag(vb + row * 32 + ((quad ^ ((row >> 1) & 3)) * 8));
#pragma unroll
      for (int qs = 0; qs < 2; ++qs)
        o[qs][nb] = __builtin_amdgcn_mfma_f32_16x16x32_bf16(pf[qs], vf, o[qs][nb], 0, 0, 0);
    }
  };

  // prologue: stage tile 0, drain (also covers qf loads), barrier
  stage(kbuf[0], vbuf[0]);
  asm volatile("s_waitcnt vmcnt(0)" ::: "memory");
  __builtin_amdgcn_s_barrier();
  __builtin_amdgcn_sched_barrier(0);

  for (int jt = 0; jt < 62; jt += 2) {
    stage(kbuf[1], vbuf[1]);            // tile jt+1
    compute(kbuf[0], vbuf[0]);          // tile jt
    __builtin_amdgcn_sched_barrier(0);
    asm volatile("s_waitcnt vmcnt(0)" ::: "memory");
    __builtin_amdgcn_s_barrier();
    __builtin_amdgcn_sched_barrier(0);

    stage(kbuf[0], vbuf[0]);            // tile jt+2
    compute(kbuf[1], vbuf[1]);          // tile jt+1
    __builtin_amdgcn_sched_barrier(0);
    asm volatile("s_waitcnt vmcnt(0)" ::: "memory");
    __builtin_amdgcn_s_barrier();
    __builtin_amdgcn_sched_barrier(0);
  }
  // tiles 62 (in buf0) and 63
  stage(kbuf[1], vbuf[1]);              // tile 63
  compute(kbuf[0], vbuf[0]);            // tile 62
  __builtin_amdgcn_sched_barrier(0);
  asm volatile("s_waitcnt vmcnt(0)" ::: "memory");
  __builtin_amdgcn_s_barrier();
  __builtin_amdgcn_sched_barrier(0);
  compute(kbuf[1], vbuf[1]);            // tile 63

#pragma unroll
  for (int qs = 0; qs < 2; ++qs) {
    float s = l_part[qs];
    s += __shfl_xor(s, 16);
    s += __shfl_xor(s, 32);
    l_part[qs] = s;
  }

#pragma unroll
  for (int qs = 0; qs < 2; ++qs) {
    float il = 1.0f / l_part[qs];
#pragma unroll
    for (int r = 0; r < 4; ++r) {
      float inv = __shfl(il, quad * 4 + r);
      int qg = q0 + wave * 32 + qs * 16 + quad * 4 + r;
#pragma unroll
      for (int nb = 0; nb < 4; ++nb) {
        float val = o[qs][nb][r] * inv;
        attn[(size_t)(b * SEQ + qg) * (NQH * HD) + h * HD + nb * 16 + l15] = f2bf(val);
      }
    }
  }
}

// ---------------- output projection (128x64 tiles, 32x64 wave-tile) ----------------
// MEASURED-BEST (R6). grid: 896 blocks (64 m-tiles x 14 n-sections), XCD-swizzled.
__global__ __launch_bounds__(256) void k_oproj(
    const ushort_t* __restrict__ attn,
    const ushort_t* __restrict__ woT,
    float* __restrict__ out) {
  __shared__ ushort_t smem[12288];
  ushort_t* sa = smem;
  ushort_t* sbb = smem + 8192;

  const int f = blockIdx.x;
  const int x = f & 7, s8 = f >> 3;   // s8: 0..111
  const int n_sect = s8 % 14;
  const int mt = (s8 / 14) * 8 + x;   // 0..63
  const int n0 = n_sect * 64;
  const int m0 = mt * 128;
  const int tid = threadIdx.x;
  const int wave = tid >> 6, lane = tid & 63;
  const int l15 = lane & 15, quad = lane >> 4;
  const int sw = l15 & 7;

  f32x4 acc[2][4];
  const f32x4 z4 = {0.f, 0.f, 0.f, 0.f};
#pragma unroll
  for (int mm = 0; mm < 2; ++mm)
#pragma unroll
    for (int nb = 0; nb < 4; ++nb) acc[mm][nb] = z4;

  for (int kt = 0; kt < 14; ++kt) {
    const int k0 = kt * 64;
    __syncthreads();
#pragma unroll
    for (int i = 0; i < 4; ++i) {
      int id = i * 256 + tid;
      int row = id >> 3;                // 0..127
      int cs = (id & 7) ^ (row & 7);
      async16(attn + (size_t)(m0 + row) * HIDDEN + k0 + cs * 8, sa + (i * 256 + wave * 64) * 8);
    }
#pragma unroll
    for (int i = 0; i < 2; ++i) {
      int id = i * 256 + tid;
      int row = id >> 3;                // 0..63
      int cs = (id & 7) ^ (row & 7);
      async16(woT + (size_t)(n0 + row) * HIDDEN + k0 + cs * 8, sbb + (i * 256 + wave * 64) * 8);
    }
    __syncthreads();
#pragma unroll
    for (int kc = 0; kc < 2; ++kc) {
      int c = kc * 4 + quad;
      bf16x8 af[2], bf[4];
#pragma unroll
      for (int mm = 0; mm < 2; ++mm)
        af[mm] = ldfrag(sa + ((wave * 32 + mm * 16 + l15) * 8 + (c ^ sw)) * 8);
#pragma unroll
      for (int nb = 0; nb < 4; ++nb)
        bf[nb] = ldfrag(sbb + ((nb * 16 + l15) * 8 + (c ^ sw)) * 8);
#pragma unroll
      for (int mm = 0; mm < 2; ++mm)
#pragma unroll
        for (int nb = 0; nb < 4; ++nb)
          acc[mm][nb] = __builtin_amdgcn_mfma_f32_16x16x32_bf16(af[mm], bf[nb], acc[mm][nb], 0, 0, 0);
    }
  }

#pragma unroll
  for (int mm = 0; mm < 2; ++mm)
#pragma unroll
    for (int nb = 0; nb < 4; ++nb)
#pragma unroll
      for (int r = 0; r < 4; ++r)
        out[(size_t)(m0 + wave * 32 + mm * 16 + quad * 4 + r) * HIDDEN +
            n0 + nb * 16 + l15] = acc[mm][nb][r];
}

// ---------------- launch ----------------

extern "C" void kernel_launch(void* const* d_in, const int* in_sizes, int n_in,
                              void* d_out, int out_size, void* d_ws, size_t ws_size,
                              hipStream_t stream) {
  (void)in_sizes; (void)n_in; (void)out_size; (void)ws_size;
  const float* hidden = (const float*)d_in[0];
  const int* pos      = (const int*)d_in[1];
  const float* Wq     = (const float*)d_in[2];
  const float* Wk     = (const float*)d_in[3];
  const float* Wv     = (const float*)d_in[4];
  const float* Wo     = (const float*)d_in[5];
  float* out = (float*)d_out;

  char* ws = (char*)d_ws;
  ushort_t* hb   = (ushort_t*)(ws);               // [8192][896] bf16   14,680,064
  ushort_t* wT   = (ushort_t*)(ws + 14680064);    // [1152][896] bf16    2,064,384
  float2*   ctab = (float2*)  (ws + 16744448);    // [2048][32]            524,288
  ushort_t* Qg   = (ushort_t*)(ws + 17268736);    // [4][14][2048][64]  14,680,064
  ushort_t* Kg   = (ushort_t*)(ws + 31948800);    // [4][2][2048][64]    2,097,152
  ushort_t* Vtg  = (ushort_t*)(ws + 34045952);    // [4][2][64][2048]    2,097,152
  ushort_t* attn = (ushort_t*)(ws + 36143104);    // [8192][896] bf16   14,680,064
  ushort_t* woT  = (ushort_t*)(ws + 50823168);    // [896][896] bf16     1,605,632

  k_prep<<<9216, dim3(32, 8), 0, stream>>>(hidden, hb, Wq, Wk, Wv, Wo, wT, woT, ctab);
  k_qkv<<<1152, 256, 0, stream>>>(hb, wT, pos, ctab, Qg, Kg, Vtg);
  k_attn<<<896, 256, 0, stream>>>(Qg, Kg, Vtg, attn);
  k_oproj<<<896, 256, 0, stream>>>(attn, woT, out);
}